// Round 22
// baseline (140.712 us; speedup 1.0000x reference)
//
#include <hip/hip_runtime.h>
#include <hip/hip_bf16.h>
#include <stdint.h>

typedef __bf16 bf16_t;
typedef __bf16 bf16x4 __attribute__((ext_vector_type(4)));
typedef __bf16 bf16x8 __attribute__((ext_vector_type(8)));
typedef float  f32x4  __attribute__((ext_vector_type(4)));
typedef unsigned u32x2 __attribute__((ext_vector_type(2)));

#define MFMA16(a,b,c) __builtin_amdgcn_mfma_f32_16x16x32_bf16((a),(b),(c),0,0,0)

static constexpr int DIM = 1024, HEADS = 16, HD = 64, NB = 2, NQ = 2048, NKK = 2048;
static constexpr int MROWS = NB * NQ; // 4096 token rows
static constexpr float SCALE_Q = 0.18033688011112042f; // 0.125 * log2(e)

// ---------------- LDS staging with chunk-XOR swizzle (bf16 source) ----------
template<int ROWS, int TPB = 256>
__device__ __forceinline__ void stage_swz(const bf16_t* gbase, int gstride, bf16_t* lds, int tid) {
#pragma unroll
  for (int c = 0; c < ROWS * 8 / TPB; ++c) {
    int p = c * TPB + tid;                        // 16B-chunk index
    int r = p >> 3, x = p & 7;
    const bf16_t* src = gbase + (size_t)r * gstride + ((x ^ (r & 7)) << 3);
    __builtin_amdgcn_global_load_lds(
        (const __attribute__((address_space(1))) void*)src,
        (__attribute__((address_space(3))) void*)(lds + (p << 3)),
        16, 0, 0);
  }
}

// ---- f32 tile staging split: loads -> regs (issue early), regs -> LDS (late).
// Produces the EXACT same LDS image as stage_swz on a bf16-converted source.
// 128 rows x 8 chunks, row stride DIM. Works for token panels AND weight
// matrices (both have row stride DIM = 1024).
__device__ __forceinline__ void loadT_f32(const float* gbase, int tid, float4* r) {
#pragma unroll
  for (int c = 0; c < 4; ++c) {
    int p = c * 256 + tid;
    int rr = p >> 3, x = p & 7;
    const float* src = gbase + (size_t)rr * DIM + ((x ^ (rr & 7)) << 3);
    r[2 * c]     = *reinterpret_cast<const float4*>(src);
    r[2 * c + 1] = *reinterpret_cast<const float4*>(src + 4);
  }
}
__device__ __forceinline__ void writeT(bf16_t* lds, int tid, const float4* r) {
#pragma unroll
  for (int c = 0; c < 4; ++c) {
    int p = c * 256 + tid;
    float4 a = r[2 * c], b2 = r[2 * c + 1];
    bf16x8 o;
    o[0] = (bf16_t)a.x;  o[1] = (bf16_t)a.y;  o[2] = (bf16_t)a.z;  o[3] = (bf16_t)a.w;
    o[4] = (bf16_t)b2.x; o[5] = (bf16_t)b2.y; o[6] = (bf16_t)b2.z; o[7] = (bf16_t)b2.w;
    *reinterpret_cast<bf16x8*>(lds + (p << 3)) = o;
  }
}

// ---- bf16 tile staging split (for gemm_out A-side).
__device__ __forceinline__ void loadT_bf16(const bf16_t* gbase, int tid, bf16x8* r) {
#pragma unroll
  for (int c = 0; c < 4; ++c) {
    int p = c * 256 + tid;
    int rr = p >> 3, x = p & 7;
    r[c] = *reinterpret_cast<const bf16x8*>(gbase + (size_t)rr * DIM + ((x ^ (rr & 7)) << 3));
  }
}
__device__ __forceinline__ void writeT16(bf16_t* lds, int tid, const bf16x8* r) {
#pragma unroll
  for (int c = 0; c < 4; ++c) {
    int p = c * 256 + tid;
    *reinterpret_cast<bf16x8*>(lds + (p << 3)) = r[c];
  }
}

__device__ __forceinline__ bf16x8 lds_read8_swz(const bf16_t* lds, int row, int chunk) {
  int sc = chunk ^ (row & 7);
  return *reinterpret_cast<const bf16x8*>(lds + row * 64 + (sc << 3));
}

__device__ __forceinline__ unsigned cvtpk_bf16(float lo, float hi) {
  unsigned r;
  asm("v_cvt_pk_bf16_f32 %0, %1, %2" : "=v"(r) : "v"(lo), "v"(hi));
  return r;
}

// ---------------- fused QKV projection GEMM (all-f32 inputs, 1-barrier) -----
// CROSS-attention: each projection has its OWN token input (q/k/v f32) AND
// reads its weight matrix DIRECTLY from f32 (no cvt_w pass). Both A and B
// are reg-staged with in-register f32->bf16 convert into dbuf LDS.
// Step t: {writeT A(t)->As[t&1]; writeT B(t)->Bs[t&1] (implicit vmcnt waits
// drain both reg-load sets); loadT A(t+1),B(t+1) into same regs (WAR safe,
// in-order); lgkmcnt(0); s_barrier; MFMA(As[t&1], Bs[t&1])}. 16 barriers.
// Hazards: writeT(t+1) vs MFMA(t-1) readers separated by barrier(t).
// LDS = 64KB -> 2 blocks/CU (binding; extra VGPR free).
__global__ __launch_bounds__(256) void gemm_qkv(const float* __restrict__ qf32,
                                                const float* __restrict__ kf32,
                                                const float* __restrict__ vf32,
                                                const float* __restrict__ Wq,
                                                const float* __restrict__ Wk,
                                                const float* __restrict__ Wv,
                                                bf16_t* __restrict__ Qp,
                                                bf16_t* __restrict__ Kp,
                                                bf16_t* __restrict__ Vt) {
  constexpr int K = DIM, N = DIM, NKI = K / 64;   // 16 K-steps
  __shared__ __align__(16) bf16_t As[2][128 * 64];
  __shared__ __align__(16) bf16_t Bs[2][128 * 64];
  const int tid = threadIdx.x;
  const int lane = tid & 63, wid = tid >> 6;
  const int l15 = lane & 15, lg = lane >> 4;
  const int wr = wid >> 1, wc = wid & 1;

  // bijective group-clustering XCD swizzle: all 8 bnl of (bm,sel) on XCD g%8
  int d = blockIdx.x + 24 * blockIdx.y;          // 0..767
  int j = d & 7, rest = d >> 3;
  int m_ = rest & 7, gq = rest >> 3;
  int g = 8 * gq + j;                            // 0..95 = (bm, sel)
  const int bm = g / 3, sel = g % 3, bnl = m_;

  const float* Af = sel == 0 ? qf32 : sel == 1 ? kf32 : vf32;
  const float* Bf = sel == 0 ? Wq : sel == 1 ? Wk : Wv;
  const float* Abase = Af + (size_t)(bm * 128) * K;
  const float* Bbase = Bf + (size_t)(bnl * 128) * K;

  f32x4 acc[4][4];
#pragma unroll
  for (int m = 0; m < 4; ++m)
#pragma unroll
    for (int n = 0; n < 4; ++n) acc[m][n] = (f32x4){0.f, 0.f, 0.f, 0.f};

  float4 rA[8], rB[8];

  loadT_f32(Abase, tid, rA);
  loadT_f32(Bbase, tid, rB);

#pragma unroll 1
  for (int t = 0; t < NKI; ++t) {
    writeT(&As[t & 1][0], tid, rA);              // waits rA loads
    writeT(&Bs[t & 1][0], tid, rB);              // waits rB loads
    if (t + 1 < NKI) {
      loadT_f32(Abase + (t + 1) * 64, tid, rA);  // WAR safe: in-order issue
      loadT_f32(Bbase + (t + 1) * 64, tid, rB);
    }
    asm volatile("s_waitcnt lgkmcnt(0)" ::: "memory");
    __builtin_amdgcn_sched_barrier(0);
    __builtin_amdgcn_s_barrier();                // tile t fully in LDS, all waves
    __builtin_amdgcn_sched_barrier(0);
#pragma unroll
    for (int kk = 0; kk < 2; ++kk) {
      bf16x8 af[4], bfr[4];
#pragma unroll
      for (int m = 0; m < 4; ++m) af[m] = lds_read8_swz(&As[t & 1][0], wr * 64 + m * 16 + l15, kk * 4 + lg);
#pragma unroll
      for (int n = 0; n < 4; ++n) bfr[n] = lds_read8_swz(&Bs[t & 1][0], wc * 64 + n * 16 + l15, kk * 4 + lg);
#pragma unroll
      for (int m = 0; m < 4; ++m)
#pragma unroll
        for (int n = 0; n < 4; ++n)
          acc[m][n] = MFMA16(af[m], bfr[n], acc[m][n]);
    }
  }

  if (sel == 2) {
    // V^T per head: Vt[((b*16+h)*64+d)*2048 + kv]
#pragma unroll
    for (int m = 0; m < 4; ++m) {
      int row0 = bm * 128 + wr * 64 + m * 16 + lg * 4;
      int bb = row0 >> 11, kv = row0 & 2047;
#pragma unroll
      for (int n = 0; n < 4; ++n) {
        int col = bnl * 128 + wc * 64 + n * 16 + l15;
        int hh = col >> 6, dd = col & 63;
        bf16x4 pk;
#pragma unroll
        for (int jj = 0; jj < 4; ++jj) pk[jj] = (bf16_t)acc[m][n][jj];
        *reinterpret_cast<bf16x4*>(Vt + (((size_t)((bb * 16 + hh) * 64 + dd)) << 11) + kv) = pk;
      }
    }
  } else {
    bf16_t* Cout = sel == 0 ? Qp : Kp;
    const float scale = sel == 0 ? SCALE_Q : 1.0f;
#pragma unroll
    for (int m = 0; m < 4; ++m)
#pragma unroll
      for (int n = 0; n < 4; ++n)
#pragma unroll
        for (int jj = 0; jj < 4; ++jj) {
          int row = bm * 128 + wr * 64 + m * 16 + lg * 4 + jj;
          int col = bnl * 128 + wc * 64 + n * 16 + l15;
          Cout[(size_t)row * N + col] = (bf16_t)(acc[m][n][jj] * scale);
        }
  }
}

// ---------------- output projection GEMM (f32 + bias, 1-barrier dbuf) -------
// A = Xa (bf16, reg-staged); B = Wo read DIRECTLY from f32 (reg-staged cvt).
__global__ __launch_bounds__(256) void gemm_out(const bf16_t* __restrict__ A,
                                                const float* __restrict__ Wo,
                                                float* __restrict__ Cout,
                                                const float* __restrict__ bias) {
  constexpr int K = DIM, N = DIM, NKI = K / 64;
  __shared__ __align__(16) bf16_t As[2][128 * 64];
  __shared__ __align__(16) bf16_t Bs[2][128 * 64];
  const int tid = threadIdx.x;
  const int lane = tid & 63, wid = tid >> 6;
  const int l15 = lane & 15, lg = lane >> 4;
  const int wr = wid >> 1, wc = wid & 1;

  int d = blockIdx.x + 8 * blockIdx.y;           // 0..255
  const int j = d & 7, bn = (d >> 3) & 7, gq = d >> 6;
  const int bm = 8 * gq + j;                     // A-panel cluster on XCD j

  const bf16_t* Abase = A + (size_t)(bm * 128) * K;
  const float*  Bbase = Wo + (size_t)(bn * 128) * K;

  f32x4 acc[4][4];
#pragma unroll
  for (int m = 0; m < 4; ++m)
#pragma unroll
    for (int n = 0; n < 4; ++n) acc[m][n] = (f32x4){0.f, 0.f, 0.f, 0.f};

  bf16x8 rA[4];
  float4 rB[8];

  loadT_bf16(Abase, tid, rA);
  loadT_f32(Bbase, tid, rB);

#pragma unroll 1
  for (int t = 0; t < NKI; ++t) {
    writeT16(&As[t & 1][0], tid, rA);            // waits rA loads
    writeT(&Bs[t & 1][0], tid, rB);              // waits rB loads
    if (t + 1 < NKI) {
      loadT_bf16(Abase + (t + 1) * 64, tid, rA);
      loadT_f32(Bbase + (t + 1) * 64, tid, rB);
    }
    asm volatile("s_waitcnt lgkmcnt(0)" ::: "memory");
    __builtin_amdgcn_sched_barrier(0);
    __builtin_amdgcn_s_barrier();
    __builtin_amdgcn_sched_barrier(0);
#pragma unroll
    for (int kk = 0; kk < 2; ++kk) {
      bf16x8 af[4], bfr[4];
#pragma unroll
      for (int m = 0; m < 4; ++m) af[m] = lds_read8_swz(&As[t & 1][0], wr * 64 + m * 16 + l15, kk * 4 + lg);
#pragma unroll
      for (int n = 0; n < 4; ++n) bfr[n] = lds_read8_swz(&Bs[t & 1][0], wc * 64 + n * 16 + l15, kk * 4 + lg);
#pragma unroll
      for (int m = 0; m < 4; ++m)
#pragma unroll
        for (int n = 0; n < 4; ++n)
          acc[m][n] = MFMA16(af[m], bfr[n], acc[m][n]);
    }
  }

#pragma unroll
  for (int m = 0; m < 4; ++m)
#pragma unroll
    for (int n = 0; n < 4; ++n)
#pragma unroll
      for (int jj = 0; jj < 4; ++jj) {
        int row = bm * 128 + wr * 64 + m * 16 + lg * 4 + jj;
        int col = bn * 128 + wc * 64 + n * 16 + l15;
        Cout[(size_t)row * N + col] = acc[m][n][jj] + bias[col];
      }
}

// ---------------- fused flash attention (R13 verbatim: PASSING, 76.8us) -----
// quad-buffer, 2-tile bodies; 8 waves x 16 q; counted vmcnt(4); 80KB LDS.
__global__ __launch_bounds__(512) void attn_fused(const bf16_t* __restrict__ Qp,
                                                  const bf16_t* __restrict__ Kp,
                                                  const bf16_t* __restrict__ Vt,
                                                  bf16_t* __restrict__ Xa) {
  __shared__ __align__(16) bf16_t Ks[4][64 * 64];
  __shared__ __align__(16) bf16_t Vs[4][64 * 64];
  __shared__ __align__(16) bf16_t Ps[8][16 * 64];   // per-wave, pad-free, row-rotated
  const int tid = threadIdx.x;
  const int lane = tid & 63, wid = tid >> 6;        // wid 0..7
  const int l15 = lane & 15, lg = lane >> 4;
  const int rot = (l15 & 7) * 8;

  // bijective XCD swizzle over 512 workgroups: XCD k hosts heads 4k..4k+3
  int id = blockIdx.x + 16 * (blockIdx.y + 16 * blockIdx.z);
  int swz = (id & 7) * 64 + (id >> 3);
  const int bx = swz & 15, h = (swz >> 4) & 15, b = swz >> 8;
  const int q0 = bx * 128;

  const bf16_t* qbase = Qp + ((size_t)(b * NQ + q0)) * DIM + h * HD;
  const bf16_t* kbase = Kp + ((size_t)b * NKK) * DIM + h * HD;
  const bf16_t* vbase = Vt + ((size_t)((b * HEADS + h) * HD)) * NKK;

  // ---- stage Q (128x64 = 16KB across Ks[0..1]) and hoist per-wave frags ----
  stage_swz<128, 512>(qbase, DIM, &Ks[0][0], tid);
  __syncthreads();
  bf16x8 qf[2];
  qf[0] = lds_read8_swz(&Ks[0][0], wid * 16 + l15, lg);
  qf[1] = lds_read8_swz(&Ks[0][0], wid * 16 + l15, 4 + lg);
  __syncthreads();   // qf reads drained before K restage

  float m_ = -1e30f, l_ = 0.f;
  f32x4 o[4];
#pragma unroll
  for (int n = 0; n < 4; ++n) o[n] = (f32x4){0.f, 0.f, 0.f, 0.f};

  constexpr int NT = NKK / 64;   // 32 kv tiles

  // ---- prologue: stage tiles 0,1 (4 loads/thread; waited in body 0) ----
  stage_swz<64, 512>(kbase, DIM, &Ks[0][0], tid);
  stage_swz<64, 512>(vbase, NKK, &Vs[0][0], tid);
  stage_swz<64, 512>(kbase + (size_t)64 * DIM, DIM, &Ks[1][0], tid);
  stage_swz<64, 512>(vbase + 64, NKK, &Vs[1][0], tid);

  for (int t = 0; t < NT; t += 2) {
    // stage tiles t+2, t+3 (4 loads/thread, left in flight past the barrier)
    if (t + 2 < NT) {
      stage_swz<64, 512>(kbase + (size_t)(t + 2) * 64 * DIM, DIM, &Ks[(t + 2) & 3][0], tid);
      stage_swz<64, 512>(vbase + (t + 2) * 64, NKK, &Vs[(t + 2) & 3][0], tid);
      stage_swz<64, 512>(kbase + (size_t)(t + 3) * 64 * DIM, DIM, &Ks[(t + 3) & 3][0], tid);
      stage_swz<64, 512>(vbase + (t + 3) * 64, NKK, &Vs[(t + 3) & 3][0], tid);
      asm volatile("s_waitcnt vmcnt(4)" ::: "memory");   // prev body's 4 landed
    } else {
      asm volatile("s_waitcnt vmcnt(0)" ::: "memory");   // tail: last 4 landed
    }
    __builtin_amdgcn_s_barrier();          // tiles t, t+1 visible to all waves
    __builtin_amdgcn_sched_barrier(0);

#pragma unroll
    for (int u = 0; u < 2; ++u) {
      const int j = t + u;
      const bf16_t* kl = &Ks[j & 3][0];
      const bf16_t* vl = &Vs[j & 3][0];

      // ---- QK(j): S^T (lane: col = q, reg jj of scur[tt] = kv 16tt+4lg+jj) --
      f32x4 scur[4];
      __builtin_amdgcn_s_setprio(1);
#pragma unroll
      for (int tt = 0; tt < 4; ++tt) {
        bf16x8 kf0 = lds_read8_swz(kl, tt * 16 + l15, lg);
        bf16x8 kf1 = lds_read8_swz(kl, tt * 16 + l15, 4 + lg);
        f32x4 a = (f32x4){0.f, 0.f, 0.f, 0.f};
        a = MFMA16(kf0, qf[0], a);
        a = MFMA16(kf1, qf[1], a);
        scur[tt] = a;
      }
      __builtin_amdgcn_s_setprio(0);

      // ---- softmax(j): lane-local + shfl_xor(16,32); defer-max (T13) ----
      float rm = scur[0][0];
#pragma unroll
      for (int tt = 0; tt < 4; ++tt)
#pragma unroll
        for (int jj = 0; jj < 4; ++jj) rm = fmaxf(rm, scur[tt][jj]);
      rm = fmaxf(rm, __shfl_xor(rm, 16));
      rm = fmaxf(rm, __shfl_xor(rm, 32));
      if (!__all(rm <= m_ + 8.f)) {
        float mn = fmaxf(m_, rm);
        float al = exp2f(m_ - mn);
        m_ = mn;
        l_ *= al;
#pragma unroll
        for (int n = 0; n < 4; ++n)
#pragma unroll
          for (int jj = 0; jj < 4; ++jj) o[n][jj] *= al;
      }
      float rs = 0.f;
#pragma unroll
      for (int tt = 0; tt < 4; ++tt)
#pragma unroll
        for (int jj = 0; jj < 4; ++jj) {
          float p = exp2f(scur[tt][jj] - m_);
          scur[tt][jj] = p;
          rs += p;
        }
      rs += __shfl_xor(rs, 16);
      rs += __shfl_xor(rs, 32);
      l_ += rs;

      // ---- P^T -> per-wave LDS: row = q (l15), col = kv rotated ----
      bf16_t* Pw = &Ps[wid][0];
#pragma unroll
      for (int tt = 0; tt < 4; ++tt) {
        unsigned w0 = cvtpk_bf16(scur[tt][0], scur[tt][1]);
        unsigned w1 = cvtpk_bf16(scur[tt][2], scur[tt][3]);
        int col = (16 * tt + 4 * lg + rot) & 63;
        u32x2 pk2 = {w0, w1};
        *reinterpret_cast<u32x2*>(reinterpret_cast<char*>(Pw) + l15 * 128 + col * 2) = pk2;
      }
      asm volatile("s_waitcnt lgkmcnt(0)" ::: "memory");
      bf16x8 pf[2];
#pragma unroll
      for (int kt = 0; kt < 2; ++kt) {
        int col = (32 * kt + 8 * lg + rot) & 63;
        pf[kt] = *reinterpret_cast<const bf16x8*>(reinterpret_cast<const char*>(Pw) + l15 * 128 + col * 2);
      }

      // ---- PV(j): O^T += V^T P^T ----
      __builtin_amdgcn_s_setprio(1);
#pragma unroll
      for (int n = 0; n < 4; ++n) {
#pragma unroll
        for (int kt = 0; kt < 2; ++kt) {
          bf16x8 vf = lds_read8_swz(vl, n * 16 + l15, 4 * kt + lg);
          o[n] = MFMA16(vf, pf[kt], o[n]);
        }
      }
      __builtin_amdgcn_s_setprio(0);
    }

    __builtin_amdgcn_s_barrier();          // all reads of tiles t,t+1 retired
    __builtin_amdgcn_sched_barrier(0);
  }

  // ---- epilogue: normalize, store (lane's q fixed; d = n*16 + 4lg + j) ----
  float inv = 1.f / l_;
  int q = q0 + wid * 16 + l15;
  bf16_t* ob = Xa + ((size_t)(b * NQ + q)) * DIM + h * HD;
#pragma unroll
  for (int n = 0; n < 4; ++n) {
    bf16x4 pk;
#pragma unroll
    for (int j = 0; j < 4; ++j) pk[j] = (bf16_t)(o[n][j] * inv);
    *reinterpret_cast<bf16x4*>(ob + n * 16 + 4 * lg) = pk;
  }
}

// ---------------- launcher (3 kernels: cvt_w eliminated) --------------------
extern "C" void kernel_launch(void* const* d_in, const int* in_sizes, int n_in,
                              void* d_out, int out_size, void* d_ws, size_t ws_size,
                              hipStream_t stream) {
  (void)in_sizes; (void)n_in; (void)out_size; (void)ws_size;
  const float* q  = (const float*)d_in[0];
  const float* k  = (const float*)d_in[1];
  const float* v  = (const float*)d_in[2];
  const float* Wq = (const float*)d_in[5];
  const float* Wk = (const float*)d_in[6];
  const float* Wv = (const float*)d_in[7];
  const float* Wo = (const float*)d_in[8];
  const float* bo = (const float*)d_in[9];
  float* out = (float*)d_out;

  bf16_t* ws = (bf16_t*)d_ws;
  const size_t SZ_IN = (size_t)MROWS * DIM;  // 4M elems
  bf16_t* Qp  = ws;
  bf16_t* Kp  = Qp + SZ_IN;
  bf16_t* Vtp = Kp + SZ_IN;
  bf16_t* Xa  = Vtp + SZ_IN;

  // fused QKV projection: tokens AND weights read directly from f32
  gemm_qkv<<<dim3(24, MROWS / 128), 256, 0, stream>>>(q, k, v, Wq, Wk, Wv,
                                                      Qp, Kp, Vtp);

  attn_fused<<<dim3(NQ / 128, HEADS, NB), 512, 0, stream>>>(Qp, Kp, Vtp, Xa);

  gemm_out<<<dim3(8, 32), 256, 0, stream>>>(Xa, Wo, out, bo);
}

// Round 23
// 138.544 us; speedup vs baseline: 1.0156x; 1.0156x over previous
//
#include <hip/hip_runtime.h>
#include <hip/hip_bf16.h>
#include <stdint.h>

typedef __bf16 bf16_t;
typedef __bf16 bf16x4 __attribute__((ext_vector_type(4)));
typedef __bf16 bf16x8 __attribute__((ext_vector_type(8)));
typedef float  f32x4  __attribute__((ext_vector_type(4)));
typedef unsigned u32x2 __attribute__((ext_vector_type(2)));

#define MFMA16(a,b,c) __builtin_amdgcn_mfma_f32_16x16x32_bf16((a),(b),(c),0,0,0)

static constexpr int DIM = 1024, HEADS = 16, HD = 64, NB = 2, NQ = 2048, NKK = 2048;
static constexpr int MROWS = NB * NQ; // 4096 token rows
static constexpr float SCALE_Q = 0.18033688011112042f; // 0.125 * log2(e)

// ---------------- f32 -> bf16 convert: WEIGHTS ONLY -------------------------
__global__ void cvt_w(const float* __restrict__ wq, const float* __restrict__ wk,
                      const float* __restrict__ wv, const float* __restrict__ wo,
                      bf16_t* wqb, bf16_t* wkb, bf16_t* wvb, bf16_t* wob) {
  const int t = blockIdx.y;
  const float* src = t == 0 ? wq : t == 1 ? wk : t == 2 ? wv : wo;
  bf16_t* dst = t == 0 ? wqb : t == 1 ? wkb : t == 2 ? wvb : wob;
  size_t i = (size_t)blockIdx.x * 256 + threadIdx.x;   // 256K float4 per weight
  float4 val = reinterpret_cast<const float4*>(src)[i];
  bf16x4 o;
  o[0] = (bf16_t)val.x; o[1] = (bf16_t)val.y; o[2] = (bf16_t)val.z; o[3] = (bf16_t)val.w;
  *reinterpret_cast<bf16x4*>(dst + i * 4) = o;
}

// ---------------- LDS staging with chunk-XOR swizzle (bf16 source) ----------
template<int ROWS, int TPB = 256>
__device__ __forceinline__ void stage_swz(const bf16_t* gbase, int gstride, bf16_t* lds, int tid) {
#pragma unroll
  for (int c = 0; c < ROWS * 8 / TPB; ++c) {
    int p = c * TPB + tid;                        // 16B-chunk index
    int r = p >> 3, x = p & 7;
    const bf16_t* src = gbase + (size_t)r * gstride + ((x ^ (r & 7)) << 3);
    __builtin_amdgcn_global_load_lds(
        (const __attribute__((address_space(1))) void*)src,
        (__attribute__((address_space(3))) void*)(lds + (p << 3)),
        16, 0, 0);
  }
}

// ---- f32 A-staging split: loads -> regs (issue early), regs -> LDS (late).
__device__ __forceinline__ void loadA_f32(const float* gbase, int tid, float4* r) {
#pragma unroll
  for (int c = 0; c < 4; ++c) {
    int p = c * 256 + tid;
    int rr = p >> 3, x = p & 7;
    const float* src = gbase + (size_t)rr * DIM + ((x ^ (rr & 7)) << 3);
    r[2 * c]     = *reinterpret_cast<const float4*>(src);
    r[2 * c + 1] = *reinterpret_cast<const float4*>(src + 4);
  }
}
__device__ __forceinline__ void writeA(bf16_t* lds, int tid, const float4* r) {
#pragma unroll
  for (int c = 0; c < 4; ++c) {
    int p = c * 256 + tid;
    float4 a = r[2 * c], b2 = r[2 * c + 1];
    bf16x8 o;
    o[0] = (bf16_t)a.x;  o[1] = (bf16_t)a.y;  o[2] = (bf16_t)a.z;  o[3] = (bf16_t)a.w;
    o[4] = (bf16_t)b2.x; o[5] = (bf16_t)b2.y; o[6] = (bf16_t)b2.z; o[7] = (bf16_t)b2.w;
    *reinterpret_cast<bf16x8*>(lds + (p << 3)) = o;
  }
}

// ---- bf16 A-staging split (for gemm_out).
__device__ __forceinline__ void loadA_bf16(const bf16_t* gbase, int tid, bf16x8* r) {
#pragma unroll
  for (int c = 0; c < 4; ++c) {
    int p = c * 256 + tid;
    int rr = p >> 3, x = p & 7;
    r[c] = *reinterpret_cast<const bf16x8*>(gbase + (size_t)rr * DIM + ((x ^ (rr & 7)) << 3));
  }
}
__device__ __forceinline__ void writeA16(bf16_t* lds, int tid, const bf16x8* r) {
#pragma unroll
  for (int c = 0; c < 4; ++c) {
    int p = c * 256 + tid;
    *reinterpret_cast<bf16x8*>(lds + (p << 3)) = r[c];
  }
}

__device__ __forceinline__ bf16x8 lds_read8_swz(const bf16_t* lds, int row, int chunk) {
  int sc = chunk ^ (row & 7);
  return *reinterpret_cast<const bf16x8*>(lds + row * 64 + (sc << 3));
}

__device__ __forceinline__ unsigned cvtpk_bf16(float lo, float hi) {
  unsigned r;
  asm("v_cvt_pk_bf16_f32 %0, %1, %2" : "=v"(r) : "v"(lo), "v"(hi));
  return r;
}

// ---------------- fused QKV projection GEMM (1-barrier, As+Bs dbuf) ---------
// Step t: {glds B(t+1)->Bs[(t+1)&1]; writeA(t)->As[t&1] (implicit vmcnt waits
// A(t) loads, also drains older B(t) glds); loadA(t+1)->rA; lgkmcnt(0);
// s_barrier; MFMA(As[t&1], Bs[t&1])}. 16 barriers (was 32).
__global__ __launch_bounds__(256) void gemm_qkv(const float* __restrict__ qf32,
                                                const float* __restrict__ kf32,
                                                const float* __restrict__ vf32,
                                                const bf16_t* __restrict__ Wq,
                                                const bf16_t* __restrict__ Wk,
                                                const bf16_t* __restrict__ Wv,
                                                bf16_t* __restrict__ Qp,
                                                bf16_t* __restrict__ Kp,
                                                bf16_t* __restrict__ Vt) {
  constexpr int K = DIM, N = DIM, NKI = K / 64;   // 16 K-steps
  __shared__ __align__(16) bf16_t As[2][128 * 64];
  __shared__ __align__(16) bf16_t Bs[2][128 * 64];
  const int tid = threadIdx.x;
  const int lane = tid & 63, wid = tid >> 6;
  const int l15 = lane & 15, lg = lane >> 4;
  const int wr = wid >> 1, wc = wid & 1;

  int d = blockIdx.x + 24 * blockIdx.y;          // 0..767
  int j = d & 7, rest = d >> 3;
  int m_ = rest & 7, gq = rest >> 3;
  int g = 8 * gq + j;                            // 0..95 = (bm, sel)
  const int bm = g / 3, sel = g % 3, bnl = m_;

  const float*  Af = sel == 0 ? qf32 : sel == 1 ? kf32 : vf32;
  const bf16_t* Bt = sel == 0 ? Wq : sel == 1 ? Wk : Wv;
  const float*  Abase = Af + (size_t)(bm * 128) * K;
  const bf16_t* Bbase = Bt + (size_t)(bnl * 128) * K;

  f32x4 acc[4][4];
#pragma unroll
  for (int m = 0; m < 4; ++m)
#pragma unroll
    for (int n = 0; n < 4; ++n) acc[m][n] = (f32x4){0.f, 0.f, 0.f, 0.f};

  float4 rA[8];

  stage_swz<128>(Bbase, K, &Bs[0][0], tid);
  loadA_f32(Abase, tid, rA);

#pragma unroll 1
  for (int t = 0; t < NKI; ++t) {
    if (t + 1 < NKI)
      stage_swz<128>(Bbase + (t + 1) * 64, K, &Bs[(t + 1) & 1][0], tid);
    writeA(&As[t & 1][0], tid, rA);              // waits A(t) loads; drains B(t)
    if (t + 1 < NKI)
      loadA_f32(Abase + (t + 1) * 64, tid, rA);
    asm volatile("s_waitcnt lgkmcnt(0)" ::: "memory");
    __builtin_amdgcn_sched_barrier(0);
    __builtin_amdgcn_s_barrier();                // tile t fully in LDS, all waves
    __builtin_amdgcn_sched_barrier(0);
#pragma unroll
    for (int kk = 0; kk < 2; ++kk) {
      bf16x8 af[4], bfr[4];
#pragma unroll
      for (int m = 0; m < 4; ++m) af[m] = lds_read8_swz(&As[t & 1][0], wr * 64 + m * 16 + l15, kk * 4 + lg);
#pragma unroll
      for (int n = 0; n < 4; ++n) bfr[n] = lds_read8_swz(&Bs[t & 1][0], wc * 64 + n * 16 + l15, kk * 4 + lg);
#pragma unroll
      for (int m = 0; m < 4; ++m)
#pragma unroll
        for (int n = 0; n < 4; ++n)
          acc[m][n] = MFMA16(af[m], bfr[n], acc[m][n]);
    }
  }

  if (sel == 2) {
#pragma unroll
    for (int m = 0; m < 4; ++m) {
      int row0 = bm * 128 + wr * 64 + m * 16 + lg * 4;
      int bb = row0 >> 11, kv = row0 & 2047;
#pragma unroll
      for (int n = 0; n < 4; ++n) {
        int col = bnl * 128 + wc * 64 + n * 16 + l15;
        int hh = col >> 6, dd = col & 63;
        bf16x4 pk;
#pragma unroll
        for (int jj = 0; jj < 4; ++jj) pk[jj] = (bf16_t)acc[m][n][jj];
        *reinterpret_cast<bf16x4*>(Vt + (((size_t)((bb * 16 + hh) * 64 + dd)) << 11) + kv) = pk;
      }
    }
  } else {
    bf16_t* Cout = sel == 0 ? Qp : Kp;
    const float scale = sel == 0 ? SCALE_Q : 1.0f;
#pragma unroll
    for (int m = 0; m < 4; ++m)
#pragma unroll
      for (int n = 0; n < 4; ++n)
#pragma unroll
        for (int jj = 0; jj < 4; ++jj) {
          int row = bm * 128 + wr * 64 + m * 16 + lg * 4 + jj;
          int col = bnl * 128 + wc * 64 + n * 16 + l15;
          Cout[(size_t)row * N + col] = (bf16_t)(acc[m][n][jj] * scale);
        }
  }
}

// ---------------- output projection GEMM (f32 + bias, 1-barrier dbuf) -------
__global__ __launch_bounds__(256) void gemm_out(const bf16_t* __restrict__ A,
                                                const bf16_t* __restrict__ Bt,
                                                float* __restrict__ Cout,
                                                const float* __restrict__ bias) {
  constexpr int K = DIM, N = DIM, NKI = K / 64;
  __shared__ __align__(16) bf16_t As[2][128 * 64];
  __shared__ __align__(16) bf16_t Bs[2][128 * 64];
  const int tid = threadIdx.x;
  const int lane = tid & 63, wid = tid >> 6;
  const int l15 = lane & 15, lg = lane >> 4;
  const int wr = wid >> 1, wc = wid & 1;

  int d = blockIdx.x + 8 * blockIdx.y;           // 0..255
  const int j = d & 7, bn = (d >> 3) & 7, gq = d >> 6;
  const int bm = 8 * gq + j;                     // A-panel cluster on XCD j

  const bf16_t* Abase = A + (size_t)(bm * 128) * K;
  const bf16_t* Bbase = Bt + (size_t)(bn * 128) * K;

  f32x4 acc[4][4];
#pragma unroll
  for (int m = 0; m < 4; ++m)
#pragma unroll
    for (int n = 0; n < 4; ++n) acc[m][n] = (f32x4){0.f, 0.f, 0.f, 0.f};

  bf16x8 rA[4];

  stage_swz<128>(Bbase, K, &Bs[0][0], tid);
  loadA_bf16(Abase, tid, rA);

#pragma unroll 1
  for (int t = 0; t < NKI; ++t) {
    if (t + 1 < NKI)
      stage_swz<128>(Bbase + (t + 1) * 64, K, &Bs[(t + 1) & 1][0], tid);
    writeA16(&As[t & 1][0], tid, rA);            // waits A(t) loads; drains B(t)
    if (t + 1 < NKI)
      loadA_bf16(Abase + (t + 1) * 64, tid, rA);
    asm volatile("s_waitcnt lgkmcnt(0)" ::: "memory");
    __builtin_amdgcn_sched_barrier(0);
    __builtin_amdgcn_s_barrier();
    __builtin_amdgcn_sched_barrier(0);
#pragma unroll
    for (int kk = 0; kk < 2; ++kk) {
      bf16x8 af[4], bfr[4];
#pragma unroll
      for (int m = 0; m < 4; ++m) af[m] = lds_read8_swz(&As[t & 1][0], wr * 64 + m * 16 + l15, kk * 4 + lg);
#pragma unroll
      for (int n = 0; n < 4; ++n) bfr[n] = lds_read8_swz(&Bs[t & 1][0], wc * 64 + n * 16 + l15, kk * 4 + lg);
#pragma unroll
      for (int m = 0; m < 4; ++m)
#pragma unroll
        for (int n = 0; n < 4; ++n)
          acc[m][n] = MFMA16(af[m], bfr[n], acc[m][n]);
    }
  }

#pragma unroll
  for (int m = 0; m < 4; ++m)
#pragma unroll
    for (int n = 0; n < 4; ++n)
#pragma unroll
      for (int jj = 0; jj < 4; ++jj) {
        int row = bm * 128 + wr * 64 + m * 16 + lg * 4 + jj;
        int col = bn * 128 + wc * 64 + n * 16 + l15;
        Cout[(size_t)row * N + col] = acc[m][n][jj] + bias[col];
      }
}

// ---------------- fused flash attention (R13 verbatim: PASSING, 76.8us) -----
// quad-buffer, 2-tile bodies; 8 waves x 16 q; counted vmcnt(4); 80KB LDS.
__global__ __launch_bounds__(512) void attn_fused(const bf16_t* __restrict__ Qp,
                                                  const bf16_t* __restrict__ Kp,
                                                  const bf16_t* __restrict__ Vt,
                                                  bf16_t* __restrict__ Xa) {
  __shared__ __align__(16) bf16_t Ks[4][64 * 64];
  __shared__ __align__(16) bf16_t Vs[4][64 * 64];
  __shared__ __align__(16) bf16_t Ps[8][16 * 64];   // per-wave, pad-free, row-rotated
  const int tid = threadIdx.x;
  const int lane = tid & 63, wid = tid >> 6;        // wid 0..7
  const int l15 = lane & 15, lg = lane >> 4;
  const int rot = (l15 & 7) * 8;

  // bijective XCD swizzle over 512 workgroups: XCD k hosts heads 4k..4k+3
  int id = blockIdx.x + 16 * (blockIdx.y + 16 * blockIdx.z);
  int swz = (id & 7) * 64 + (id >> 3);
  const int bx = swz & 15, h = (swz >> 4) & 15, b = swz >> 8;
  const int q0 = bx * 128;

  const bf16_t* qbase = Qp + ((size_t)(b * NQ + q0)) * DIM + h * HD;
  const bf16_t* kbase = Kp + ((size_t)b * NKK) * DIM + h * HD;
  const bf16_t* vbase = Vt + ((size_t)((b * HEADS + h) * HD)) * NKK;

  // ---- stage Q (128x64 = 16KB across Ks[0..1]) and hoist per-wave frags ----
  stage_swz<128, 512>(qbase, DIM, &Ks[0][0], tid);
  __syncthreads();
  bf16x8 qf[2];
  qf[0] = lds_read8_swz(&Ks[0][0], wid * 16 + l15, lg);
  qf[1] = lds_read8_swz(&Ks[0][0], wid * 16 + l15, 4 + lg);
  __syncthreads();   // qf reads drained before K restage

  float m_ = -1e30f, l_ = 0.f;
  f32x4 o[4];
#pragma unroll
  for (int n = 0; n < 4; ++n) o[n] = (f32x4){0.f, 0.f, 0.f, 0.f};

  constexpr int NT = NKK / 64;   // 32 kv tiles

  // ---- prologue: stage tiles 0,1 (4 loads/thread; waited in body 0) ----
  stage_swz<64, 512>(kbase, DIM, &Ks[0][0], tid);
  stage_swz<64, 512>(vbase, NKK, &Vs[0][0], tid);
  stage_swz<64, 512>(kbase + (size_t)64 * DIM, DIM, &Ks[1][0], tid);
  stage_swz<64, 512>(vbase + 64, NKK, &Vs[1][0], tid);

  for (int t = 0; t < NT; t += 2) {
    // stage tiles t+2, t+3 (4 loads/thread, left in flight past the barrier)
    if (t + 2 < NT) {
      stage_swz<64, 512>(kbase + (size_t)(t + 2) * 64 * DIM, DIM, &Ks[(t + 2) & 3][0], tid);
      stage_swz<64, 512>(vbase + (t + 2) * 64, NKK, &Vs[(t + 2) & 3][0], tid);
      stage_swz<64, 512>(kbase + (size_t)(t + 3) * 64 * DIM, DIM, &Ks[(t + 3) & 3][0], tid);
      stage_swz<64, 512>(vbase + (t + 3) * 64, NKK, &Vs[(t + 3) & 3][0], tid);
      asm volatile("s_waitcnt vmcnt(4)" ::: "memory");   // prev body's 4 landed
    } else {
      asm volatile("s_waitcnt vmcnt(0)" ::: "memory");   // tail: last 4 landed
    }
    __builtin_amdgcn_s_barrier();          // tiles t, t+1 visible to all waves
    __builtin_amdgcn_sched_barrier(0);

#pragma unroll
    for (int u = 0; u < 2; ++u) {
      const int j = t + u;
      const bf16_t* kl = &Ks[j & 3][0];
      const bf16_t* vl = &Vs[j & 3][0];

      // ---- QK(j): S^T (lane: col = q, reg jj of scur[tt] = kv 16tt+4lg+jj) --
      f32x4 scur[4];
      __builtin_amdgcn_s_setprio(1);
#pragma unroll
      for (int tt = 0; tt < 4; ++tt) {
        bf16x8 kf0 = lds_read8_swz(kl, tt * 16 + l15, lg);
        bf16x8 kf1 = lds_read8_swz(kl, tt * 16 + l15, 4 + lg);
        f32x4 a = (f32x4){0.f, 0.f, 0.f, 0.f};
        a = MFMA16(kf0, qf[0], a);
        a = MFMA16(kf1, qf[1], a);
        scur[tt] = a;
      }
      __builtin_amdgcn_s_setprio(0);

      // ---- softmax(j): lane-local + shfl_xor(16,32); defer-max (T13) ----
      float rm = scur[0][0];
#pragma unroll
      for (int tt = 0; tt < 4; ++tt)
#pragma unroll
        for (int jj = 0; jj < 4; ++jj) rm = fmaxf(rm, scur[tt][jj]);
      rm = fmaxf(rm, __shfl_xor(rm, 16));
      rm = fmaxf(rm, __shfl_xor(rm, 32));
      if (!__all(rm <= m_ + 8.f)) {
        float mn = fmaxf(m_, rm);
        float al = exp2f(m_ - mn);
        m_ = mn;
        l_ *= al;
#pragma unroll
        for (int n = 0; n < 4; ++n)
#pragma unroll
          for (int jj = 0; jj < 4; ++jj) o[n][jj] *= al;
      }
      float rs = 0.f;
#pragma unroll
      for (int tt = 0; tt < 4; ++tt)
#pragma unroll
        for (int jj = 0; jj < 4; ++jj) {
          float p = exp2f(scur[tt][jj] - m_);
          scur[tt][jj] = p;
          rs += p;
        }
      rs += __shfl_xor(rs, 16);
      rs += __shfl_xor(rs, 32);
      l_ += rs;

      // ---- P^T -> per-wave LDS: row = q (l15), col = kv rotated ----
      bf16_t* Pw = &Ps[wid][0];
#pragma unroll
      for (int tt = 0; tt < 4; ++tt) {
        unsigned w0 = cvtpk_bf16(scur[tt][0], scur[tt][1]);
        unsigned w1 = cvtpk_bf16(scur[tt][2], scur[tt][3]);
        int col = (16 * tt + 4 * lg + rot) & 63;
        u32x2 pk2 = {w0, w1};
        *reinterpret_cast<u32x2*>(reinterpret_cast<char*>(Pw) + l15 * 128 + col * 2) = pk2;
      }
      asm volatile("s_waitcnt lgkmcnt(0)" ::: "memory");
      bf16x8 pf[2];
#pragma unroll
      for (int kt = 0; kt < 2; ++kt) {
        int col = (32 * kt + 8 * lg + rot) & 63;
        pf[kt] = *reinterpret_cast<const bf16x8*>(reinterpret_cast<const char*>(Pw) + l15 * 128 + col * 2);
      }

      // ---- PV(j): O^T += V^T P^T ----
      __builtin_amdgcn_s_setprio(1);
#pragma unroll
      for (int n = 0; n < 4; ++n) {
#pragma unroll
        for (int kt = 0; kt < 2; ++kt) {
          bf16x8 vf = lds_read8_swz(vl, n * 16 + l15, 4 * kt + lg);
          o[n] = MFMA16(vf, pf[kt], o[n]);
        }
      }
      __builtin_amdgcn_s_setprio(0);
    }

    __builtin_amdgcn_s_barrier();          // all reads of tiles t,t+1 retired
    __builtin_amdgcn_sched_barrier(0);
  }

  // ---- epilogue: normalize, store (lane's q fixed; d = n*16 + 4lg + j) ----
  float inv = 1.f / l_;
  int q = q0 + wid * 16 + l15;
  bf16_t* ob = Xa + ((size_t)(b * NQ + q)) * DIM + h * HD;
#pragma unroll
  for (int n = 0; n < 4; ++n) {
    bf16x4 pk;
#pragma unroll
    for (int j = 0; j < 4; ++j) pk[j] = (bf16_t)(o[n][j] * inv);
    *reinterpret_cast<bf16x4*>(ob + n * 16 + 4 * lg) = pk;
  }
}

// ---------------- launcher ----------------
extern "C" void kernel_launch(void* const* d_in, const int* in_sizes, int n_in,
                              void* d_out, int out_size, void* d_ws, size_t ws_size,
                              hipStream_t stream) {
  (void)in_sizes; (void)n_in; (void)out_size; (void)ws_size;
  const float* q  = (const float*)d_in[0];
  const float* k  = (const float*)d_in[1];
  const float* v  = (const float*)d_in[2];
  const float* Wq = (const float*)d_in[5];
  const float* Wk = (const float*)d_in[6];
  const float* Wv = (const float*)d_in[7];
  const float* Wo = (const float*)d_in[8];
  const float* bo = (const float*)d_in[9];
  float* out = (float*)d_out;

  bf16_t* ws = (bf16_t*)d_ws;
  const size_t SZ_IN = (size_t)MROWS * DIM;  // 4M elems
  const size_t SZ_W  = (size_t)DIM * DIM;    // 1M elems
  bf16_t* qb  = ws;                 // (unused region kept for layout stability)
  bf16_t* kb  = qb  + SZ_IN;
  bf16_t* vb  = kb  + SZ_IN;
  bf16_t* wqb = vb  + SZ_IN;
  bf16_t* wkb = wqb + SZ_W;
  bf16_t* wvb = wkb + SZ_W;
  bf16_t* wob = wvb + SZ_W;
  bf16_t* Qp  = wob + SZ_W;
  bf16_t* Kp  = Qp  + SZ_IN;
  bf16_t* Vtp = Kp  + SZ_IN;
  bf16_t* Xa  = qb;  // alias: qb region free (q/k/v converts fused into GEMM)

  // weights only: 4 x 1M elems
  cvt_w<<<dim3(1024, 4), 256, 0, stream>>>(Wq, Wk, Wv, Wo, wqb, wkb, wvb, wob);

  // fused QKV projection (1-barrier dbuf pipeline)
  gemm_qkv<<<dim3(24, MROWS / 128), 256, 0, stream>>>(q, k, v, wqb, wkb, wvb,
                                                      Qp, Kp, Vtp);

  attn_fused<<<dim3(NQ / 128, HEADS, NB), 512, 0, stream>>>(Qp, Kp, Vtp, Xa);

  gemm_out<<<dim3(8, 32), 256, 0, stream>>>(Xa, wob, out, bo);
}